// Round 2
// baseline (1594.872 us; speedup 1.0000x reference)
//
#include <hip/hip_runtime.h>

#define N_USERS 10000
#define N_ITEMS 40000
#define N_TOTAL 50000
#define HID     64
#define BATCH   8192
#define HOPS    3
#define KDIM    10000          // M == K == 10000 for social GEMM
#define KTILES  157            // ceil(10000/64)
#define KPAD    (KTILES * 64)  // 10048
#define SPLITK  4

// output segment offsets (flat f32-element offsets into d_out)
#define O0 0
#define O1 524288
#define O2 1048576
#define O3 1572864
#define O4 2212864
#define O5 2852864
#define O6 3377152
#define O7 3901440
#define O8 4425728
#define O9 4950016
#define O10 5474304

typedef __attribute__((ext_vector_type(8))) short short8;
typedef __attribute__((ext_vector_type(4))) float floatx4;
typedef __attribute__((ext_vector_type(4))) unsigned short ushort4v;
typedef __attribute__((ext_vector_type(8))) unsigned short ushort8v;

__device__ __forceinline__ unsigned short f32bf(float f) {
  union { float f; unsigned u; } v; v.f = f;
  unsigned r = v.u + 0x7fffu + ((v.u >> 16) & 1u);
  return (unsigned short)(r >> 16);
}

// ---------------- init ----------------
__global__ void init_social(const float* __restrict__ ue, const float* __restrict__ u1,
                            float* __restrict__ Hcur, float* __restrict__ Hacc) {
  int i = blockIdx.x * 256 + threadIdx.x;          // over 10000*64
  if (i >= N_USERS * HID) return;
  int r = i >> 6, c = i & 63;
  float a = ue[i], b = u1[i];
  size_t p = (size_t)r * 128 + c;
  Hcur[p] = a; Hcur[p + 64] = b;
  Hacc[p] = a; Hacc[p + 64] = b;
}

__global__ void init_ui(const float* __restrict__ ue, const float* __restrict__ ie,
                        const float* __restrict__ u2, const float* __restrict__ i2,
                        float* __restrict__ Ecur, float* __restrict__ Eacc) {
  int i = blockIdx.x * 256 + threadIdx.x;          // over 50000*64
  if (i >= N_TOTAL * HID) return;
  int r = i >> 6;
  float a, b;
  if (r < N_USERS) { a = ue[i]; b = u2[i]; }
  else             { a = ie[i - N_USERS * HID]; b = i2[i - N_USERS * HID]; }
  size_t p = (size_t)r * 128 + (i & 63);
  Ecur[p] = a; Ecur[p + 64] = b;
  Eacc[p] = a; Eacc[p + 64] = b;
}

// ---------------- CSR build ----------------
__global__ void hist_rows(const int* __restrict__ rows, int* __restrict__ counts, int n) {
  int i = blockIdx.x * 256 + threadIdx.x;
  if (i < n) atomicAdd(&counts[rows[i]], 1);
}

// block = 256 threads, 4 elems each (1024/block); writes per-block-exclusive into offs, total into bsum
__global__ void scan1(const int* __restrict__ counts, int* __restrict__ offs, int* __restrict__ bsum) {
  __shared__ int sh[256];
  int t = threadIdx.x;
  int base = blockIdx.x * 1024 + t * 4;
  int v0 = 0, v1 = 0, v2 = 0, v3 = 0;
  if (base + 0 < N_TOTAL) v0 = counts[base + 0];
  if (base + 1 < N_TOTAL) v1 = counts[base + 1];
  if (base + 2 < N_TOTAL) v2 = counts[base + 2];
  if (base + 3 < N_TOTAL) v3 = counts[base + 3];
  int s = v0 + v1 + v2 + v3;
  sh[t] = s;
  __syncthreads();
  for (int d = 1; d < 256; d <<= 1) {
    int x = (t >= d) ? sh[t - d] : 0;
    __syncthreads();
    sh[t] += x;
    __syncthreads();
  }
  int excl = sh[t] - s;
  if (t == 255) bsum[blockIdx.x] = sh[255];
  if (base + 0 < N_TOTAL) offs[base + 0] = excl; excl += v0;
  if (base + 1 < N_TOTAL) offs[base + 1] = excl; excl += v1;
  if (base + 2 < N_TOTAL) offs[base + 2] = excl; excl += v2;
  if (base + 3 < N_TOTAL) offs[base + 3] = excl;
}

__global__ void scan2(int* __restrict__ bsum, int nb) {  // single block, 64 threads
  __shared__ int sh[64];
  int t = threadIdx.x;
  int v = (t < nb) ? bsum[t] : 0;
  sh[t] = v;
  __syncthreads();
  for (int d = 1; d < 64; d <<= 1) {
    int x = (t >= d) ? sh[t - d] : 0;
    __syncthreads();
    sh[t] += x;
    __syncthreads();
  }
  if (t < nb) bsum[t] = sh[t] - v;  // exclusive
}

__global__ void scan3(int* __restrict__ offs, const int* __restrict__ bexcl,
                      int* __restrict__ cursor, int nnz) {
  int i = blockIdx.x * 256 + threadIdx.x;
  if (i < N_TOTAL) {
    int v = offs[i] + bexcl[i >> 10];
    offs[i] = v; cursor[i] = v;
  }
  if (i == 0) offs[N_TOTAL] = nnz;
}

__global__ void scatter_csr(const int* __restrict__ rows, const int* __restrict__ cols,
                            const float* __restrict__ vals, int* __restrict__ cursor,
                            int* __restrict__ ccol, float* __restrict__ cval, int n) {
  int i = blockIdx.x * 256 + threadIdx.x;
  if (i < n) {
    int p = atomicAdd(&cursor[rows[i]], 1);
    ccol[p] = cols[i];
    cval[p] = vals[i];
  }
}

// ---------------- social GEMM ----------------
// Hcur [10000][128] f32 -> Ht [128][10048] bf16 (k-padded with zeros)
__global__ __launch_bounds__(256)
void transpose_bf16(const float* __restrict__ H, unsigned short* __restrict__ Ht) {
  __shared__ __align__(16) float ts[64 * 132];
  int k0 = blockIdx.x * 64;
  int t = threadIdx.x;
#pragma unroll
  for (int i = 0; i < 8; i++) {
    int f = t + i * 256;                 // float4 id 0..2047
    int r = f >> 5, c4 = (f & 31) * 4;
    float4 v = make_float4(0.f, 0.f, 0.f, 0.f);
    if (k0 + r < KDIM) v = *(const float4*)&H[(size_t)(k0 + r) * 128 + c4];
    *(float4*)&ts[r * 132 + c4] = v;
  }
  __syncthreads();
#pragma unroll
  for (int i = 0; i < 4; i++) {
    int g = t + i * 256;                 // 0..1023
    int n = g >> 3, ko = (g & 7) * 8;
    ushort8v o;
#pragma unroll
    for (int j = 0; j < 8; j++) o[j] = f32bf(ts[(ko + j) * 132 + n]);
    *(ushort8v*)&Ht[(size_t)n * KPAD + k0 + ko] = o;
  }
}

// C[10000][128] += S[10000][10000](f32, cast bf16 on stage) @ H (via Ht bf16)
__global__ __launch_bounds__(256)
void social_gemm(const float* __restrict__ S, const unsigned short* __restrict__ Bt,
                 float* __restrict__ C) {
  __shared__ __align__(16) unsigned short As[64 * 72];   // row-pad 72 -> 144B stride (16B-aligned, 2-way banks)
  __shared__ __align__(16) unsigned short Bs[128 * 72];
  int m0 = blockIdx.x * 64;
  int ks = blockIdx.y;
  int t0 = (ks * KTILES) / SPLITK;
  int t1 = ((ks + 1) * KTILES) / SPLITK;
  int tid = threadIdx.x;
  int wave = tid >> 6, lane = tid & 63;
  int mq = lane & 15, quad = lane >> 4;

  floatx4 acc[8];
#pragma unroll
  for (int i = 0; i < 8; i++) acc[i] = (floatx4){0.f, 0.f, 0.f, 0.f};

  int ar = tid >> 2;                 // 0..63  (A stage row)
  int aq = tid & 3;                  // 0..3   (16-f32 quarter)
  bool rok = (m0 + ar) < KDIM;
  const float* arow = S + (size_t)(m0 + ar) * KDIM;
  int bn = tid >> 3;                 // 0..31
  int bk = (tid & 7) * 8;            // 0..56

  for (int t = t0; t < t1; ++t) {
    int k0 = t * 64;
    // stage A (fp32 global -> bf16 LDS)
#pragma unroll
    for (int i = 0; i < 4; i++) {
      int kk = k0 + aq * 16 + i * 4;
      float4 v = make_float4(0.f, 0.f, 0.f, 0.f);
      if (rok && kk < KDIM) v = *(const float4*)(arow + kk);
      ushort4v b4;
      b4.x = f32bf(v.x); b4.y = f32bf(v.y); b4.z = f32bf(v.z); b4.w = f32bf(v.w);
      *(ushort4v*)&As[ar * 72 + aq * 16 + i * 4] = b4;
    }
    // stage B (bf16 global, pre-transposed, pre-padded)
#pragma unroll
    for (int i = 0; i < 4; i++) {
      int n = bn + i * 32;
      *(ushort8v*)&Bs[n * 72 + bk] = *(const ushort8v*)&Bt[(size_t)n * KPAD + k0 + bk];
    }
    __syncthreads();
#pragma unroll
    for (int kk = 0; kk < 64; kk += 32) {
      short8 a = *(const short8*)&As[(wave * 16 + mq) * 72 + kk + quad * 8];
#pragma unroll
      for (int nt = 0; nt < 8; nt++) {
        short8 b = *(const short8*)&Bs[(nt * 16 + mq) * 72 + kk + quad * 8];
        acc[nt] = __builtin_amdgcn_mfma_f32_16x16x32_bf16(a, b, acc[nt], 0, 0, 0);
      }
    }
    __syncthreads();
  }
  // epilogue: split-K atomic accumulate (C zeroed before launch)
#pragma unroll
  for (int nt = 0; nt < 8; nt++) {
    int col = nt * 16 + mq;
    int rbase = m0 + wave * 16 + quad * 4;
#pragma unroll
    for (int i = 0; i < 4; i++) {
      int r = rbase + i;
      if (r < KDIM) atomicAdd(&C[(size_t)r * 128 + col], acc[nt][i]);
    }
  }
}

// ---------------- UI sparse hop (one wave per destination row) ----------------
__global__ __launch_bounds__(256)
void ui_hop(const int* __restrict__ offs, const int* __restrict__ ccol,
            const float* __restrict__ cval, const float* __restrict__ Ein,
            float* __restrict__ Eout) {
  int wid = blockIdx.x * 4 + (threadIdx.x >> 6);   // row id, grid covers exactly 50000
  int lane = threadIdx.x & 63;
  int s = offs[wid], e = offs[wid + 1];
  float ax = 0.f, ay = 0.f;
  int j = s;
  for (; j + 4 <= e; j += 4) {
    int c0 = ccol[j], c1 = ccol[j + 1], c2 = ccol[j + 2], c3 = ccol[j + 3];
    float w0 = cval[j], w1 = cval[j + 1], w2 = cval[j + 2], w3 = cval[j + 3];
    float2 p0 = *(const float2*)&Ein[(size_t)c0 * 128 + lane * 2];
    float2 p1 = *(const float2*)&Ein[(size_t)c1 * 128 + lane * 2];
    float2 p2 = *(const float2*)&Ein[(size_t)c2 * 128 + lane * 2];
    float2 p3 = *(const float2*)&Ein[(size_t)c3 * 128 + lane * 2];
    ax += w0 * p0.x + w1 * p1.x + w2 * p2.x + w3 * p3.x;
    ay += w0 * p0.y + w1 * p1.y + w2 * p2.y + w3 * p3.y;
  }
  for (; j < e; ++j) {
    int c = ccol[j]; float w = cval[j];
    float2 p = *(const float2*)&Ein[(size_t)c * 128 + lane * 2];
    ax += w * p.x; ay += w * p.y;
  }
  float2 o; o.x = ax; o.y = ay;
  *(float2*)&Eout[(size_t)wid * 128 + lane * 2] = o;   // full overwrite: no pre-zero needed
}

__global__ void acc_add(float* __restrict__ acc, const float* __restrict__ h, int n4) {
  int i = blockIdx.x * 256 + threadIdx.x;
  if (i < n4) {
    float4* a = (float4*)acc;
    const float4* b = (const float4*)h;
    float4 x = a[i], y = b[i];
    x.x += y.x; x.y += y.y; x.z += y.z; x.w += y.w;
    a[i] = x;
  }
}

// ---------------- outputs (f32) ----------------
__global__ void full_out(const float* __restrict__ HSacc, const float* __restrict__ Eacc,
                         float* __restrict__ out) {
  int i = blockIdx.x * 256 + threadIdx.x;         // over 10000*64
  if (i >= N_USERS * HID) return;
  int r = i >> 6, c = i & 63;
  out[O3 + i] = HSacc[(size_t)r * 128 + c] * 0.25f;
  out[O4 + i] = Eacc[(size_t)r * 128 + c] * 0.25f;
}

__global__ void gather_out(const int* __restrict__ users, const int* __restrict__ pos,
                           const int* __restrict__ neg, const float* __restrict__ HSacc,
                           const float* __restrict__ Eacc, const float* __restrict__ item1,
                           float* __restrict__ out) {
  int b = blockIdx.x * 4 + (threadIdx.x >> 6);    // grid covers exactly 8192
  int lane = threadIdx.x & 63;
  int u = users[b], p = pos[b], n = neg[b];
  const float q = 0.25f;
  float us = HSacc[(size_t)u * 128 + lane] * q;
  float ua = Eacc[(size_t)u * 128 + lane] * q;
  size_t bl = (size_t)b * 64 + lane;
  out[O0 + bl]  = 0.5f * (us + ua);
  out[O1 + bl]  = Eacc[(size_t)(N_USERS + p) * 128 + lane] * q;
  out[O2 + bl]  = Eacc[(size_t)(N_USERS + n) * 128 + lane] * q;
  out[O5 + bl]  = HSacc[(size_t)u * 128 + 64 + lane] * q;
  out[O6 + bl]  = item1[(size_t)p * 64 + lane];
  out[O7 + bl]  = item1[(size_t)n * 64 + lane];
  out[O8 + bl]  = Eacc[(size_t)u * 128 + 64 + lane] * q;
  out[O9 + bl]  = Eacc[(size_t)(N_USERS + p) * 128 + 64 + lane] * q;
  out[O10 + bl] = Eacc[(size_t)(N_USERS + n) * 128 + 64 + lane] * q;
}

extern "C" void kernel_launch(void* const* d_in, const int* in_sizes, int n_in,
                              void* d_out, int out_size, void* d_ws, size_t ws_size,
                              hipStream_t stream) {
  (void)n_in; (void)out_size; (void)ws_size;
  const int*   users = (const int*)d_in[0];
  const int*   pos   = (const int*)d_in[1];
  const int*   neg   = (const int*)d_in[2];
  const float* ue    = (const float*)d_in[3];
  const float* ie    = (const float*)d_in[4];
  const float* u1    = (const float*)d_in[5];
  const float* i1    = (const float*)d_in[6];
  const float* u2    = (const float*)d_in[7];
  const float* i2    = (const float*)d_in[8];
  const float* S     = (const float*)d_in[9];
  const int*   Arows = (const int*)d_in[10];
  const int*   Acols = (const int*)d_in[11];
  const float* Avals = (const float*)d_in[12];
  const int nnz = in_sizes[10];

  char* ws = (char*)d_ws;
  size_t off = 0;
  auto alloc = [&](size_t b) { size_t r = off; off += (b + 255) & ~(size_t)255; return r; };
  float* HS0   = (float*)(ws + alloc(sizeof(float) * (size_t)N_USERS * 128));
  float* HS1   = (float*)(ws + alloc(sizeof(float) * (size_t)N_USERS * 128));
  float* HSacc = (float*)(ws + alloc(sizeof(float) * (size_t)N_USERS * 128));
  unsigned short* Ht = (unsigned short*)(ws + alloc(sizeof(short) * (size_t)128 * KPAD));
  float* E0    = (float*)(ws + alloc(sizeof(float) * (size_t)N_TOTAL * 128));
  float* E1    = (float*)(ws + alloc(sizeof(float) * (size_t)N_TOTAL * 128));
  float* Eacc  = (float*)(ws + alloc(sizeof(float) * (size_t)N_TOTAL * 128));
  int* counts  = (int*)(ws + alloc(sizeof(int) * (N_TOTAL + 16)));
  int* offs    = (int*)(ws + alloc(sizeof(int) * (N_TOTAL + 16)));
  int* cursor  = (int*)(ws + alloc(sizeof(int) * (N_TOTAL + 16)));
  int* bsum    = (int*)(ws + alloc(sizeof(int) * 256));
  int* ccol    = (int*)(ws + alloc(sizeof(int) * (size_t)nnz));
  float* cval  = (float*)(ws + alloc(sizeof(float) * (size_t)nnz));

  // init ego tensors (128 cols: [0:64]=run A, [64:128]=run B)
  init_social<<<2500, 256, 0, stream>>>(ue, u1, HS0, HSacc);
  init_ui<<<12500, 256, 0, stream>>>(ue, ie, u2, i2, E0, Eacc);

  // CSR build (per call; ws is re-poisoned each launch)
  hipMemsetAsync(counts, 0, sizeof(int) * (N_TOTAL + 16), stream);
  hist_rows<<<(nnz + 255) / 256, 256, 0, stream>>>(Arows, counts, nnz);
  scan1<<<49, 256, 0, stream>>>(counts, offs, bsum);
  scan2<<<1, 64, 0, stream>>>(bsum, 49);
  scan3<<<196, 256, 0, stream>>>(offs, bsum, cursor, nnz);
  scatter_csr<<<(nnz + 255) / 256, 256, 0, stream>>>(Arows, Acols, Avals, cursor, ccol, cval, nnz);

  float* hc = HS0; float* hn = HS1;
  float* ec = E0;  float* en = E1;
  for (int h = 0; h < HOPS; ++h) {
    // social: h = S @ h
    transpose_bf16<<<KTILES, 256, 0, stream>>>(hc, Ht);
    hipMemsetAsync(hn, 0, sizeof(float) * (size_t)N_USERS * 128, stream);
    social_gemm<<<dim3(KTILES, SPLITK), 256, 0, stream>>>(S, Ht, hn);
    acc_add<<<1250, 256, 0, stream>>>(HSacc, hn, (N_USERS * 128) / 4);
    { float* t = hc; hc = hn; hn = t; }
    // ui: h = A @ h (CSR, atomic-free)
    ui_hop<<<12500, 256, 0, stream>>>(offs, ccol, cval, ec, en);
    acc_add<<<6250, 256, 0, stream>>>(Eacc, en, (N_TOTAL * 128) / 4);
    { float* t = ec; ec = en; en = t; }
  }

  float* out = (float*)d_out;
  full_out<<<2500, 256, 0, stream>>>(HSacc, Eacc, out);
  gather_out<<<2048, 256, 0, stream>>>(users, pos, neg, HSacc, Eacc, i1, out);
}